// Round 12
// baseline (164.704 us; speedup 1.0000x reference)
//
#include <hip/hip_runtime.h>
#include <math.h>

// Problem: B=16, LQ=1024, LK=1024, DK=256, DV=256, fp32 in/out, mask int32.
// Identity: softmax_k(q_s + k_s with mask) == mask-weighted softmax of k_s alone
// (q_s cancels; masked entries are exactly -1e9 -> weight 0). query never read.
// k_s ~ N(0,256) => softmax mass concentrates in top ~30-60 keys; chunk-0
// (top-64) provably terminates ~all rows (e_64 ~ e^-26 * Z << 1e-5 * Z).
//
// R1: counting-sort select. R2 (FAIL): scalar chains. R3-R7: per-row walks
// latency-bound (best R4 50us). R8 (FAIL): explicit reg pipeline -> VGPR 156.
// R9/R11 (44-46us attn): 4 rows/wave walk w/ scalar-selected weights works,
//   but 64KB LDS staging caps the kernel at 2 blocks/CU and grid=512 gives
//   each CU exactly 2 serial blocks -> no cross-block overlap; 1.3 TB/s.
// R12: R11 minus LDS minus barrier. V read directly in the walk as wave-
//   uniform coalesced 1KB loads (L2-hot: 16 batch top-64 sets = 1MB; total
//   re-read 256MB ~ 7us at L2 BW). 256-thr blocks x 1024 -> 4+ blocks/CU
//   (VGPR ~70, no LDS) so prologue streams overlap walk compute across
//   blocks. Walk: fixed 64 iters, unroll 8 -> 8 loads in flight/wave.

#define NB     16
#define NL     1024     // LQ == LK
#define ND     256      // DK == DV
#define NBKT   128      // buckets of width 1.0 in log-space

// ---------------- Kernel A: ks[b,k] = dot(key[b,k,:], w) -----------------
__global__ __launch_bounds__(256)
void ks_kernel(const float* __restrict__ key, const float* __restrict__ w,
               float* __restrict__ ks) {
    int wid  = threadIdx.x >> 6;
    int lane = threadIdx.x & 63;
    int row  = blockIdx.x * 4 + wid;               // 0 .. NB*NL-1
    const float4* krow = (const float4*)(key + (size_t)row * ND);
    float4 kv = krow[lane];
    float4 wv = ((const float4*)w)[lane];
    float p = kv.x * wv.x + kv.y * wv.y + kv.z * wv.z + kv.w * wv.w;
    #pragma unroll
    for (int off = 32; off > 0; off >>= 1)
        p += __shfl_xor(p, off, 64);
    if (lane == 0) ks[row] = p;
}

// ------- Kernel B: per batch: max, e=exp(ks-m), counting sort by -------
// ------- bucket floor(m-v), exact suffix mass at chunk boundaries -------
// 256 threads (4 waves), 4 entries/thread. Order within a bucket arbitrary;
// attn breaks on the EXACT suffix mass rem[] of the actual gathered order.
__global__ __launch_bounds__(256)
void select_kernel(const float* __restrict__ ks,
                   float2* __restrict__ pk, float* __restrict__ rem) {
    __shared__ float se[NL];       // gathered e values (bucket order)
    __shared__ int   cnt[NBKT];    // histogram
    __shared__ int   cur[NBKT];    // scan -> scatter cursors
    __shared__ float wred[4];      // per-wave max
    __shared__ float csum[16];     // per-chunk sums
    const int b    = blockIdx.x;
    const int t    = threadIdx.x;
    const int lane = t & 63;
    const int wid  = t >> 6;
    const float* ksb = ks + b * NL;

    if (t < NBKT) cnt[t] = 0;

    // 4 entries per thread, coalesced (stride 256)
    float v0 = ksb[t], v1 = ksb[t + 256], v2 = ksb[t + 512], v3 = ksb[t + 768];

    // block max: thread max4 -> wave shuffle reduce -> 4-way LDS combine
    float mx = fmaxf(fmaxf(v0, v1), fmaxf(v2, v3));
    #pragma unroll
    for (int off = 32; off > 0; off >>= 1)
        mx = fmaxf(mx, __shfl_xor(mx, off, 64));
    if (lane == 0) wred[wid] = mx;
    __syncthreads();                                        // #1 (also covers cnt=0)
    const float m = fmaxf(fmaxf(wred[0], wred[1]), fmaxf(wred[2], wred[3]));

    float e0 = __expf(v0 - m), e1 = __expf(v1 - m);
    float e2 = __expf(v2 - m), e3 = __expf(v3 - m);
    int b0 = (int)fminf(m - v0, (float)(NBKT - 1));
    int b1 = (int)fminf(m - v1, (float)(NBKT - 1));
    int b2 = (int)fminf(m - v2, (float)(NBKT - 1));
    int b3 = (int)fminf(m - v3, (float)(NBKT - 1));
    atomicAdd(&cnt[b0], 1); atomicAdd(&cnt[b1], 1);
    atomicAdd(&cnt[b2], 1); atomicAdd(&cnt[b3], 1);
    __syncthreads();                                        // #2

    // exclusive scan of cnt[128] by wave 0 via shuffles (no barriers inside)
    if (wid == 0) {
        int a  = cnt[lane];
        int b2v = cnt[lane + 64];
        int sa = a, sb = b2v;
        #pragma unroll
        for (int d = 1; d < 64; d <<= 1) {
            int na = __shfl_up(sa, d, 64);
            int nb = __shfl_up(sb, d, 64);
            if (lane >= d) { sa += na; sb += nb; }
        }
        int tot = __shfl(sa, 63, 64);
        sb += tot;
        cur[lane]      = sa - a;
        cur[lane + 64] = sb - b2v;
    }
    __syncthreads();                                        // #3

    // scatter (bijective: every entry gets a unique p in [0, NL))
    int p0 = atomicAdd(&cur[b0], 1);
    int p1 = atomicAdd(&cur[b1], 1);
    int p2 = atomicAdd(&cur[b2], 1);
    int p3 = atomicAdd(&cur[b3], 1);
    se[p0] = e0; pk[b * NL + p0] = make_float2(e0, __int_as_float(t));
    se[p1] = e1; pk[b * NL + p1] = make_float2(e1, __int_as_float(t + 256));
    se[p2] = e2; pk[b * NL + p2] = make_float2(e2, __int_as_float(t + 512));
    se[p3] = e3; pk[b * NL + p3] = make_float2(e3, __int_as_float(t + 768));
    __syncthreads();                                        // #4

    // per-chunk sums: wave w reduces chunks 4w..4w+3
    #pragma unroll
    for (int cc = 0; cc < 4; ++cc) {
        int chunk = wid * 4 + cc;
        float s = se[chunk * 64 + lane];
        #pragma unroll
        for (int off = 32; off > 0; off >>= 1)
            s += __shfl_xor(s, off, 64);
        if (lane == 0) csum[chunk] = s;
    }
    __syncthreads();                                        // #5

    // suffix masses at the 16 boundary slots attn actually reads
    if (t == 0) {
        float run = 0.0f;
        for (int c = 15; c >= 0; --c) {
            rem[b * NL + c * 64 + 63] = run;
            run += csum[c];
        }
    }
}

// ---------------- Kernel C: out[b,q,:] = sum_k p * value[b,k,:] ----------
// 256 threads = 4 waves; ONE WAVE = 4 ROWS of one batch; block = 16 rows;
// grid 1024. No LDS arrays, no barriers -> 4+ blocks/CU. Prologue: 16
// coalesced int4 mask loads (R6 pattern) + pk float2, all independent; then
// bits -> bpermute -> ballot -> butterfly Z per row. Walk: fixed 64 iters,
// unroll 8; per iter one wave-uniform 1KB V load (L2-hot) feeds 4
// accumulators via scalar-selected weights.
__global__ __launch_bounds__(256)
void attn_kernel(const float* __restrict__ value, const int* __restrict__ mask,
                 const float2* __restrict__ pk, const float* __restrict__ rem,
                 float* __restrict__ out) {
    const int wid  = threadIdx.x >> 6;        // 0..3
    const int lane = threadIdx.x & 63;
    const int row0 = blockIdx.x * 16 + wid * 4;   // wave's 4 rows
    const int b    = row0 >> 10;
    const int base = b << 10;

    const float4* vbase = (const float4*)(value + ((size_t)b << 10) * ND);
    const float2* pk_g  = pk + base;

    // ---- prologue: issue all independent global loads first ----
    // mask rows, fully coalesced: load j covers columns 256j + 4*lane + (0..3)
    const int4* mr0 = (const int4*)(mask + (size_t)(row0 + 0) * NL);
    const int4* mr1 = (const int4*)(mask + (size_t)(row0 + 1) * NL);
    const int4* mr2 = (const int4*)(mask + (size_t)(row0 + 2) * NL);
    const int4* mr3 = (const int4*)(mask + (size_t)(row0 + 3) * NL);
    int4 a00 = mr0[lane], a01 = mr0[lane + 64], a02 = mr0[lane + 128], a03 = mr0[lane + 192];
    int4 a10 = mr1[lane], a11 = mr1[lane + 64], a12 = mr1[lane + 128], a13 = mr1[lane + 192];
    int4 a20 = mr2[lane], a21 = mr2[lane + 64], a22 = mr2[lane + 128], a23 = mr2[lane + 192];
    int4 a30 = mr3[lane], a31 = mr3[lane + 64], a32 = mr3[lane + 128], a33 = mr3[lane + 192];

    // top-64 metadata, lane-parallel (shared by all rows of the batch)
    float2 p0 = pk_g[lane];
    int   k0  = __float_as_int(p0.y);
    float e0  = p0.x;
    int   e0i = __float_as_int(e0);

    // ---- bits per row: bit (4j + c) = column 256j + 4*lane + c ----
    auto mkbits = [](int4 x0, int4 x1, int4 x2, int4 x3) -> unsigned int {
        unsigned int bits = 0;
        bits |= (x0.x != 0 ? 1u : 0u) << 0;  bits |= (x0.y != 0 ? 1u : 0u) << 1;
        bits |= (x0.z != 0 ? 1u : 0u) << 2;  bits |= (x0.w != 0 ? 1u : 0u) << 3;
        bits |= (x1.x != 0 ? 1u : 0u) << 4;  bits |= (x1.y != 0 ? 1u : 0u) << 5;
        bits |= (x1.z != 0 ? 1u : 0u) << 6;  bits |= (x1.w != 0 ? 1u : 0u) << 7;
        bits |= (x2.x != 0 ? 1u : 0u) << 8;  bits |= (x2.y != 0 ? 1u : 0u) << 9;
        bits |= (x2.z != 0 ? 1u : 0u) << 10; bits |= (x2.w != 0 ? 1u : 0u) << 11;
        bits |= (x3.x != 0 ? 1u : 0u) << 12; bits |= (x3.y != 0 ? 1u : 0u) << 13;
        bits |= (x3.z != 0 ? 1u : 0u) << 14; bits |= (x3.w != 0 ? 1u : 0u) << 15;
        return bits;
    };
    unsigned int bits0 = mkbits(a00, a01, a02, a03);
    unsigned int bits1 = mkbits(a10, a11, a12, a13);
    unsigned int bits2 = mkbits(a20, a21, a22, a23);
    unsigned int bits3 = mkbits(a30, a31, a32, a33);

    // bit for column k0: lane (k0>>2)&63, bit (k0&3) + 4*(k0>>8)  (R6 mapping)
    const int addr  = ((k0 >> 2) & 63) << 2;
    const int shift = (k0 & 3) + ((k0 >> 8) << 2);
    bool mb0 = (((unsigned int)__builtin_amdgcn_ds_bpermute(addr, (int)bits0)) >> shift) & 1u;
    bool mb1 = (((unsigned int)__builtin_amdgcn_ds_bpermute(addr, (int)bits1)) >> shift) & 1u;
    bool mb2 = (((unsigned int)__builtin_amdgcn_ds_bpermute(addr, (int)bits2)) >> shift) & 1u;
    bool mb3 = (((unsigned int)__builtin_amdgcn_ds_bpermute(addr, (int)bits3)) >> shift) & 1u;
    unsigned long long bm0 = __ballot(mb0);
    unsigned long long bm1 = __ballot(mb1);
    unsigned long long bm2 = __ballot(mb2);
    unsigned long long bm3 = __ballot(mb3);

    // Z per row: butterfly of mask-selected e (uniform result)
    auto zsum = [&](bool mb) -> float {
        float wz = mb ? e0 : 0.0f;
        #pragma unroll
        for (int off = 32; off > 0; off >>= 1)
            wz += __shfl_xor(wz, off, 64);
        return wz;
    };
    float z0 = zsum(mb0), z1 = zsum(mb1), z2 = zsum(mb2), z3 = zsum(mb3);

    // ---- walk: fixed 64 iterations; uniform L2-hot V loads; scalar weights ----
    float4 acc0 = make_float4(0.f, 0.f, 0.f, 0.f);
    float4 acc1 = make_float4(0.f, 0.f, 0.f, 0.f);
    float4 acc2 = make_float4(0.f, 0.f, 0.f, 0.f);
    float4 acc3 = make_float4(0.f, 0.f, 0.f, 0.f);

    #pragma unroll 8
    for (int i = 0; i < 64; ++i) {
        int s    = __builtin_amdgcn_readlane(k0, i);     // uniform -> SGPR base
        float4 v = vbase[(size_t)s * 64 + lane];         // coalesced 1KB, L2-hot
        float ei = __int_as_float(__builtin_amdgcn_readlane(e0i, i));
        float w0 = ((bm0 >> i) & 1ull) ? ei : 0.0f;      // s_cselect
        float w1 = ((bm1 >> i) & 1ull) ? ei : 0.0f;
        float w2 = ((bm2 >> i) & 1ull) ? ei : 0.0f;
        float w3 = ((bm3 >> i) & 1ull) ? ei : 0.0f;
        acc0.x += w0 * v.x; acc0.y += w0 * v.y; acc0.z += w0 * v.z; acc0.w += w0 * v.w;
        acc1.x += w1 * v.x; acc1.y += w1 * v.y; acc1.z += w1 * v.z; acc1.w += w1 * v.w;
        acc2.x += w2 * v.x; acc2.y += w2 * v.y; acc2.z += w2 * v.z; acc2.w += w2 * v.w;
        acc3.x += w3 * v.x; acc3.y += w3 * v.y; acc3.z += w3 * v.z; acc3.w += w3 * v.w;
    }

    // ---- per-row epilogue: done check, rare deep chunks, store ----
    const float remv = rem[base + 63];

    auto finish_row = [&](int r, float4 acc, float Z) {
        const int* mrow = mask + (size_t)(row0 + r) * NL;
        bool done = (remv <= 1e-5f * Z);     // Z==0 -> rem>0 -> continue
        for (int c = 1; c < 16 && !done; ++c) {           // ~never taken
            float2 p = pk_g[c * 64 + lane];
            float e  = p.x;
            int   k  = __float_as_int(p.y);
            bool mb  = (mrow[k] != 0);
            float dz = mb ? e : 0.0f;
            #pragma unroll
            for (int off = 32; off > 0; off >>= 1)
                dz += __shfl_xor(dz, off, 64);
            unsigned long long bmx = __ballot(mb);
            int eI = __float_as_int(e);
            for (int i = 0; i < 64; ++i) {                // rolled: rare path
                float ei = __int_as_float(__builtin_amdgcn_readlane(eI, i));
                int   ki = __builtin_amdgcn_readlane(k, i);
                float w  = ((bmx >> i) & 1ull) ? ei : 0.0f;
                float4 v = vbase[(size_t)ki * 64 + lane];
                acc.x += w * v.x; acc.y += w * v.y;
                acc.z += w * v.z; acc.w += w * v.w;
            }
            Z += dz;
            done = (rem[base + c * 64 + 63] <= 1e-5f * Z);
        }
        float4* orow = (float4*)(out + (size_t)(row0 + r) * ND);
        if (Z > 0.0f) {
            float inv = 1.0f / Z;
            orow[lane] = make_float4(acc.x * inv, acc.y * inv,
                                     acc.z * inv, acc.w * inv);
        } else {
            // all-masked row: softmax over constant -1e9 -> uniform average
            float4 s = make_float4(0.f, 0.f, 0.f, 0.f);
            for (int k = 0; k < NL; ++k) {
                float4 v = vbase[(size_t)k * 64 + lane];
                s.x += v.x; s.y += v.y; s.z += v.z; s.w += v.w;
            }
            const float inv = 1.0f / (float)NL;
            orow[lane] = make_float4(s.x * inv, s.y * inv, s.z * inv, s.w * inv);
        }
    };
    finish_row(0, acc0, z0);
    finish_row(1, acc1, z1);
    finish_row(2, acc2, z2);
    finish_row(3, acc3, z3);
}

extern "C" void kernel_launch(void* const* d_in, const int* in_sizes, int n_in,
                              void* d_out, int out_size, void* d_ws, size_t ws_size,
                              hipStream_t stream) {
    // setup_inputs order: query, key, value, w, mask   (query unused!)
    const float* key   = (const float*)d_in[1];
    const float* value = (const float*)d_in[2];
    const float* w     = (const float*)d_in[3];
    const int*   mask  = (const int*)d_in[4];
    float*       outp  = (float*)d_out;

    float*  ks  = (float*)d_ws;                  // 16*1024 f32
    float2* pkb = (float2*)(ks + NB * NL);       // 16*1024 f32x2 (e, idx) bucket-desc
    float*  rem = (float*)(pkb + NB * NL);       // 16*1024 f32 suffix masses

    ks_kernel    <<<NB * NL / 4, 256, 0, stream>>>(key, w, ks);
    select_kernel<<<NB, 256, 0, stream>>>(ks, pkb, rem);
    attn_kernel  <<<NB * NL / 16, 256, 0, stream>>>(value, mask, pkb, rem, outp);
}

// Round 13
// 164.176 us; speedup vs baseline: 1.0032x; 1.0032x over previous
//
#include <hip/hip_runtime.h>
#include <math.h>

// Problem: B=16, LQ=1024, LK=1024, DK=256, DV=256, fp32 in/out, mask int32.
// Identity: softmax_k(q_s + k_s with mask) == mask-weighted softmax of k_s alone
// (q_s cancels; masked entries are exactly -1e9 -> weight 0). query never read.
// k_s ~ N(0,256) => softmax mass concentrates in top ~30-60 keys; chunk-0
// (top-64) provably terminates ~all rows (e_64 ~ e^-26 * Z << 1e-5 * Z).
//
// R1: counting-sort select. R2 (FAIL): scalar chains. R3-R7: per-row walks
// latency-bound (best R4 50us). R8 (FAIL): reg pipeline -> VGPR 156, occ 6%.
// R9/R11 (44-46us): 4 rows/wave LDS walk + scalar-selected weights.
// R12 (52us): dropping LDS hurt; occupancy is NOT the stream limiter (fills
//   hit 6.6 TB/s at 8% occ). Common flaw of R4-R12: each wave issues ONE
//   mask burst then stalls on it -> per-CU HBM demand spikes then dies ->
//   1.1 TB/s time-averaged.
// R13: intra-wave pipeline of the mask stream. 8 rows/wave in two halves:
//   issue maskA(rows 0-3) -> stage V -> barrier -> bits A -> ISSUE maskB
//   (rows 4-7) -> walk A over LDS (~2000cy, hides B's HBM latency) ->
//   bits B -> walk B -> epilogues. V stays in LDS (no prefetch registers).
//   256-thr blocks x 512, 64KB LDS, 2 blocks/CU; LDS reads/row unchanged.

#define NB     16
#define NL     1024     // LQ == LK
#define ND     256      // DK == DV
#define NBKT   128      // buckets of width 1.0 in log-space

// ---------------- Kernel A: ks[b,k] = dot(key[b,k,:], w) -----------------
__global__ __launch_bounds__(256)
void ks_kernel(const float* __restrict__ key, const float* __restrict__ w,
               float* __restrict__ ks) {
    int wid  = threadIdx.x >> 6;
    int lane = threadIdx.x & 63;
    int row  = blockIdx.x * 4 + wid;               // 0 .. NB*NL-1
    const float4* krow = (const float4*)(key + (size_t)row * ND);
    float4 kv = krow[lane];
    float4 wv = ((const float4*)w)[lane];
    float p = kv.x * wv.x + kv.y * wv.y + kv.z * wv.z + kv.w * wv.w;
    #pragma unroll
    for (int off = 32; off > 0; off >>= 1)
        p += __shfl_xor(p, off, 64);
    if (lane == 0) ks[row] = p;
}

// ------- Kernel B: per batch: max, e=exp(ks-m), counting sort by -------
// ------- bucket floor(m-v), exact suffix mass at chunk boundaries -------
// 256 threads (4 waves), 4 entries/thread. Order within a bucket arbitrary;
// attn breaks on the EXACT suffix mass rem[] of the actual gathered order.
__global__ __launch_bounds__(256)
void select_kernel(const float* __restrict__ ks,
                   float2* __restrict__ pk, float* __restrict__ rem) {
    __shared__ float se[NL];       // gathered e values (bucket order)
    __shared__ int   cnt[NBKT];    // histogram
    __shared__ int   cur[NBKT];    // scan -> scatter cursors
    __shared__ float wred[4];      // per-wave max
    __shared__ float csum[16];     // per-chunk sums
    const int b    = blockIdx.x;
    const int t    = threadIdx.x;
    const int lane = t & 63;
    const int wid  = t >> 6;
    const float* ksb = ks + b * NL;

    if (t < NBKT) cnt[t] = 0;

    // 4 entries per thread, coalesced (stride 256)
    float v0 = ksb[t], v1 = ksb[t + 256], v2 = ksb[t + 512], v3 = ksb[t + 768];

    // block max: thread max4 -> wave shuffle reduce -> 4-way LDS combine
    float mx = fmaxf(fmaxf(v0, v1), fmaxf(v2, v3));
    #pragma unroll
    for (int off = 32; off > 0; off >>= 1)
        mx = fmaxf(mx, __shfl_xor(mx, off, 64));
    if (lane == 0) wred[wid] = mx;
    __syncthreads();                                        // #1 (also covers cnt=0)
    const float m = fmaxf(fmaxf(wred[0], wred[1]), fmaxf(wred[2], wred[3]));

    float e0 = __expf(v0 - m), e1 = __expf(v1 - m);
    float e2 = __expf(v2 - m), e3 = __expf(v3 - m);
    int b0 = (int)fminf(m - v0, (float)(NBKT - 1));
    int b1 = (int)fminf(m - v1, (float)(NBKT - 1));
    int b2 = (int)fminf(m - v2, (float)(NBKT - 1));
    int b3 = (int)fminf(m - v3, (float)(NBKT - 1));
    atomicAdd(&cnt[b0], 1); atomicAdd(&cnt[b1], 1);
    atomicAdd(&cnt[b2], 1); atomicAdd(&cnt[b3], 1);
    __syncthreads();                                        // #2

    // exclusive scan of cnt[128] by wave 0 via shuffles (no barriers inside)
    if (wid == 0) {
        int a  = cnt[lane];
        int b2v = cnt[lane + 64];
        int sa = a, sb = b2v;
        #pragma unroll
        for (int d = 1; d < 64; d <<= 1) {
            int na = __shfl_up(sa, d, 64);
            int nb = __shfl_up(sb, d, 64);
            if (lane >= d) { sa += na; sb += nb; }
        }
        int tot = __shfl(sa, 63, 64);
        sb += tot;
        cur[lane]      = sa - a;
        cur[lane + 64] = sb - b2v;
    }
    __syncthreads();                                        // #3

    // scatter (bijective: every entry gets a unique p in [0, NL))
    int p0 = atomicAdd(&cur[b0], 1);
    int p1 = atomicAdd(&cur[b1], 1);
    int p2 = atomicAdd(&cur[b2], 1);
    int p3 = atomicAdd(&cur[b3], 1);
    se[p0] = e0; pk[b * NL + p0] = make_float2(e0, __int_as_float(t));
    se[p1] = e1; pk[b * NL + p1] = make_float2(e1, __int_as_float(t + 256));
    se[p2] = e2; pk[b * NL + p2] = make_float2(e2, __int_as_float(t + 512));
    se[p3] = e3; pk[b * NL + p3] = make_float2(e3, __int_as_float(t + 768));
    __syncthreads();                                        // #4

    // per-chunk sums: wave w reduces chunks 4w..4w+3
    #pragma unroll
    for (int cc = 0; cc < 4; ++cc) {
        int chunk = wid * 4 + cc;
        float s = se[chunk * 64 + lane];
        #pragma unroll
        for (int off = 32; off > 0; off >>= 1)
            s += __shfl_xor(s, off, 64);
        if (lane == 0) csum[chunk] = s;
    }
    __syncthreads();                                        // #5

    // suffix masses at the 16 boundary slots attn actually reads
    if (t == 0) {
        float run = 0.0f;
        for (int c = 15; c >= 0; --c) {
            rem[b * NL + c * 64 + 63] = run;
            run += csum[c];
        }
    }
}

// ---------------- Kernel C: out[b,q,:] = sum_k p * value[b,k,:] ----------
// 256 threads = 4 waves; ONE WAVE = 8 ROWS, processed in two staggered
// halves so the second half's mask loads are in flight during the first
// half's LDS walk. Block = 32 rows; grid 512; 64KB LDS (top-64 V rows),
// 2 blocks/CU. Weights scalar-selected from SGPR ballot masks (R11 walk).
__global__ __launch_bounds__(256)
void attn_kernel(const float* __restrict__ value, const int* __restrict__ mask,
                 const float2* __restrict__ pk, const float* __restrict__ rem,
                 float* __restrict__ out) {
    __shared__ float lds_V[64 * ND];          // 64 KB: top-64 value rows

    const int wid  = threadIdx.x >> 6;        // 0..3
    const int lane = threadIdx.x & 63;
    const int row0 = blockIdx.x * 32 + wid * 8;   // wave's 8 rows
    const int b    = row0 >> 10;
    const int base = b << 10;

    const float4* vbase = (const float4*)(value + ((size_t)b << 10) * ND);
    const float2* pk_g  = pk + base;

    // top-64 metadata, lane-parallel (shared by all rows of the batch)
    float2 p0 = pk_g[lane];
    int   k0  = __float_as_int(p0.y);
    float e0  = p0.x;
    int   e0i = __float_as_int(e0);

    // ---- half A: issue mask loads for rows 0-3 (R6 coalesced pattern) ----
    const int4* mr0 = (const int4*)(mask + (size_t)(row0 + 0) * NL);
    const int4* mr1 = (const int4*)(mask + (size_t)(row0 + 1) * NL);
    const int4* mr2 = (const int4*)(mask + (size_t)(row0 + 2) * NL);
    const int4* mr3 = (const int4*)(mask + (size_t)(row0 + 3) * NL);
    int4 a00 = mr0[lane], a01 = mr0[lane + 64], a02 = mr0[lane + 128], a03 = mr0[lane + 192];
    int4 a10 = mr1[lane], a11 = mr1[lane + 64], a12 = mr1[lane + 128], a13 = mr1[lane + 192];
    int4 a20 = mr2[lane], a21 = mr2[lane + 64], a22 = mr2[lane + 128], a23 = mr2[lane + 192];
    int4 a30 = mr3[lane], a31 = mr3[lane + 64], a32 = mr3[lane + 128], a33 = mr3[lane + 192];

    // stage top-64 V rows: wave w stages slots 16w..16w+15 (coalesced 1KB)
    #pragma unroll
    for (int j = 0; j < 16; ++j) {
        int s   = wid * 16 + j;
        int ksr = __builtin_amdgcn_readlane(k0, s);    // uniform -> SGPR base
        ((float4*)lds_V)[s * 64 + lane] = vbase[(size_t)ksr * 64 + lane];
    }

    // bits: bit (4j + c) = column 256j + 4*lane + c
    auto mkbits = [](int4 x0, int4 x1, int4 x2, int4 x3) -> unsigned int {
        unsigned int bits = 0;
        bits |= (x0.x != 0 ? 1u : 0u) << 0;  bits |= (x0.y != 0 ? 1u : 0u) << 1;
        bits |= (x0.z != 0 ? 1u : 0u) << 2;  bits |= (x0.w != 0 ? 1u : 0u) << 3;
        bits |= (x1.x != 0 ? 1u : 0u) << 4;  bits |= (x1.y != 0 ? 1u : 0u) << 5;
        bits |= (x1.z != 0 ? 1u : 0u) << 6;  bits |= (x1.w != 0 ? 1u : 0u) << 7;
        bits |= (x2.x != 0 ? 1u : 0u) << 8;  bits |= (x2.y != 0 ? 1u : 0u) << 9;
        bits |= (x2.z != 0 ? 1u : 0u) << 10; bits |= (x2.w != 0 ? 1u : 0u) << 11;
        bits |= (x3.x != 0 ? 1u : 0u) << 12; bits |= (x3.y != 0 ? 1u : 0u) << 13;
        bits |= (x3.z != 0 ? 1u : 0u) << 14; bits |= (x3.w != 0 ? 1u : 0u) << 15;
        return bits;
    };
    const int addr  = ((k0 >> 2) & 63) << 2;          // R6 bit location mapping
    const int shift = (k0 & 3) + ((k0 >> 8) << 2);

    unsigned int bits0 = mkbits(a00, a01, a02, a03);
    unsigned int bits1 = mkbits(a10, a11, a12, a13);
    unsigned int bits2 = mkbits(a20, a21, a22, a23);
    unsigned int bits3 = mkbits(a30, a31, a32, a33);

    // ---- half B: issue mask loads for rows 4-7 NOW (hide under walk A) ----
    const int4* mr4 = (const int4*)(mask + (size_t)(row0 + 4) * NL);
    const int4* mr5 = (const int4*)(mask + (size_t)(row0 + 5) * NL);
    const int4* mr6 = (const int4*)(mask + (size_t)(row0 + 6) * NL);
    const int4* mr7 = (const int4*)(mask + (size_t)(row0 + 7) * NL);
    int4 b40 = mr4[lane], b41 = mr4[lane + 64], b42 = mr4[lane + 128], b43 = mr4[lane + 192];
    int4 b50 = mr5[lane], b51 = mr5[lane + 64], b52 = mr5[lane + 128], b53 = mr5[lane + 192];
    int4 b60 = mr6[lane], b61 = mr6[lane + 64], b62 = mr6[lane + 128], b63 = mr6[lane + 192];
    int4 b70 = mr7[lane], b71 = mr7[lane + 64], b72 = mr7[lane + 128], b73 = mr7[lane + 192];

    bool mb0 = (((unsigned int)__builtin_amdgcn_ds_bpermute(addr, (int)bits0)) >> shift) & 1u;
    bool mb1 = (((unsigned int)__builtin_amdgcn_ds_bpermute(addr, (int)bits1)) >> shift) & 1u;
    bool mb2 = (((unsigned int)__builtin_amdgcn_ds_bpermute(addr, (int)bits2)) >> shift) & 1u;
    bool mb3 = (((unsigned int)__builtin_amdgcn_ds_bpermute(addr, (int)bits3)) >> shift) & 1u;
    unsigned long long bm0 = __ballot(mb0);
    unsigned long long bm1 = __ballot(mb1);
    unsigned long long bm2 = __ballot(mb2);
    unsigned long long bm3 = __ballot(mb3);

    auto zsum = [&](bool mb) -> float {
        float wz = mb ? e0 : 0.0f;
        #pragma unroll
        for (int off = 32; off > 0; off >>= 1)
            wz += __shfl_xor(wz, off, 64);
        return wz;
    };
    float z0 = zsum(mb0), z1 = zsum(mb1), z2 = zsum(mb2), z3 = zsum(mb3);

    __syncthreads();   // lds_V ready

    // ---- walk A: rows 0-3 over LDS (hides half-B HBM latency) ----
    float4 acc0 = make_float4(0.f,0.f,0.f,0.f), acc1 = make_float4(0.f,0.f,0.f,0.f);
    float4 acc2 = make_float4(0.f,0.f,0.f,0.f), acc3 = make_float4(0.f,0.f,0.f,0.f);
    #pragma unroll 16
    for (int i = 0; i < 64; ++i) {
        float4 v = ((const float4*)lds_V)[i * 64 + lane];
        float ei = __int_as_float(__builtin_amdgcn_readlane(e0i, i));
        float w0 = ((bm0 >> i) & 1ull) ? ei : 0.0f;
        float w1 = ((bm1 >> i) & 1ull) ? ei : 0.0f;
        float w2 = ((bm2 >> i) & 1ull) ? ei : 0.0f;
        float w3 = ((bm3 >> i) & 1ull) ? ei : 0.0f;
        acc0.x += w0*v.x; acc0.y += w0*v.y; acc0.z += w0*v.z; acc0.w += w0*v.w;
        acc1.x += w1*v.x; acc1.y += w1*v.y; acc1.z += w1*v.z; acc1.w += w1*v.w;
        acc2.x += w2*v.x; acc2.y += w2*v.y; acc2.z += w2*v.z; acc2.w += w2*v.w;
        acc3.x += w3*v.x; acc3.y += w3*v.y; acc3.z += w3*v.z; acc3.w += w3*v.w;
    }

    // ---- resolve half B (loads should have landed under walk A) ----
    unsigned int bits4 = mkbits(b40, b41, b42, b43);
    unsigned int bits5 = mkbits(b50, b51, b52, b53);
    unsigned int bits6 = mkbits(b60, b61, b62, b63);
    unsigned int bits7 = mkbits(b70, b71, b72, b73);
    bool mb4 = (((unsigned int)__builtin_amdgcn_ds_bpermute(addr, (int)bits4)) >> shift) & 1u;
    bool mb5 = (((unsigned int)__builtin_amdgcn_ds_bpermute(addr, (int)bits5)) >> shift) & 1u;
    bool mb6 = (((unsigned int)__builtin_amdgcn_ds_bpermute(addr, (int)bits6)) >> shift) & 1u;
    bool mb7 = (((unsigned int)__builtin_amdgcn_ds_bpermute(addr, (int)bits7)) >> shift) & 1u;
    unsigned long long bm4 = __ballot(mb4);
    unsigned long long bm5 = __ballot(mb5);
    unsigned long long bm6 = __ballot(mb6);
    unsigned long long bm7 = __ballot(mb7);
    float z4 = zsum(mb4), z5 = zsum(mb5), z6 = zsum(mb6), z7 = zsum(mb7);

    // ---- walk B: rows 4-7 over LDS ----
    float4 acc4 = make_float4(0.f,0.f,0.f,0.f), acc5 = make_float4(0.f,0.f,0.f,0.f);
    float4 acc6 = make_float4(0.f,0.f,0.f,0.f), acc7 = make_float4(0.f,0.f,0.f,0.f);
    #pragma unroll 16
    for (int i = 0; i < 64; ++i) {
        float4 v = ((const float4*)lds_V)[i * 64 + lane];
        float ei = __int_as_float(__builtin_amdgcn_readlane(e0i, i));
        float w4 = ((bm4 >> i) & 1ull) ? ei : 0.0f;
        float w5 = ((bm5 >> i) & 1ull) ? ei : 0.0f;
        float w6 = ((bm6 >> i) & 1ull) ? ei : 0.0f;
        float w7 = ((bm7 >> i) & 1ull) ? ei : 0.0f;
        acc4.x += w4*v.x; acc4.y += w4*v.y; acc4.z += w4*v.z; acc4.w += w4*v.w;
        acc5.x += w5*v.x; acc5.y += w5*v.y; acc5.z += w5*v.z; acc5.w += w5*v.w;
        acc6.x += w6*v.x; acc6.y += w6*v.y; acc6.z += w6*v.z; acc6.w += w6*v.w;
        acc7.x += w7*v.x; acc7.y += w7*v.y; acc7.z += w7*v.z; acc7.w += w7*v.w;
    }

    // ---- per-row epilogue: done check, rare deep chunks, store ----
    const float remv = rem[base + 63];

    auto finish_row = [&](int r, float4 acc, float Z) {
        const int* mrow = mask + (size_t)(row0 + r) * NL;
        bool done = (remv <= 1e-5f * Z);     // Z==0 -> rem>0 -> continue
        for (int c = 1; c < 16 && !done; ++c) {           // ~never taken
            float2 p = pk_g[c * 64 + lane];
            float e  = p.x;
            int   k  = __float_as_int(p.y);
            bool mb  = (mrow[k] != 0);
            float dz = mb ? e : 0.0f;
            #pragma unroll
            for (int off = 32; off > 0; off >>= 1)
                dz += __shfl_xor(dz, off, 64);
            unsigned long long bmx = __ballot(mb);
            int eI = __float_as_int(e);
            for (int i = 0; i < 64; ++i) {                // rolled: rare path
                float ei = __int_as_float(__builtin_amdgcn_readlane(eI, i));
                int   ki = __builtin_amdgcn_readlane(k, i);
                float w  = ((bmx >> i) & 1ull) ? ei : 0.0f;
                float4 v = vbase[(size_t)ki * 64 + lane];
                acc.x += w * v.x; acc.y += w * v.y;
                acc.z += w * v.z; acc.w += w * v.w;
            }
            Z += dz;
            done = (rem[base + c * 64 + 63] <= 1e-5f * Z);
        }
        float4* orow = (float4*)(out + (size_t)(row0 + r) * ND);
        if (Z > 0.0f) {
            float inv = 1.0f / Z;
            orow[lane] = make_float4(acc.x * inv, acc.y * inv,
                                     acc.z * inv, acc.w * inv);
        } else {
            // all-masked row: softmax over constant -1e9 -> uniform average
            float4 s = make_float4(0.f, 0.f, 0.f, 0.f);
            for (int k = 0; k < NL; ++k) {
                float4 v = vbase[(size_t)k * 64 + lane];
                s.x += v.x; s.y += v.y; s.z += v.z; s.w += v.w;
            }
            const float inv = 1.0f / (float)NL;
            orow[lane] = make_float4(s.x * inv, s.y * inv, s.z * inv, s.w * inv);
        }
    };
    finish_row(0, acc0, z0);
    finish_row(1, acc1, z1);
    finish_row(2, acc2, z2);
    finish_row(3, acc3, z3);
    finish_row(4, acc4, z4);
    finish_row(5, acc5, z5);
    finish_row(6, acc6, z6);
    finish_row(7, acc7, z7);
}

extern "C" void kernel_launch(void* const* d_in, const int* in_sizes, int n_in,
                              void* d_out, int out_size, void* d_ws, size_t ws_size,
                              hipStream_t stream) {
    // setup_inputs order: query, key, value, w, mask   (query unused!)
    const float* key   = (const float*)d_in[1];
    const float* value = (const float*)d_in[2];
    const float* w     = (const float*)d_in[3];
    const int*   mask  = (const int*)d_in[4];
    float*       outp  = (float*)d_out;

    float*  ks  = (float*)d_ws;                  // 16*1024 f32
    float2* pkb = (float2*)(ks + NB * NL);       // 16*1024 f32x2 (e, idx) bucket-desc
    float*  rem = (float*)(pkb + NB * NL);       // 16*1024 f32 suffix masses

    ks_kernel    <<<NB * NL / 4, 256, 0, stream>>>(key, w, ks);
    select_kernel<<<NB, 256, 0, stream>>>(ks, pkb, rem);
    attn_kernel  <<<NB * NL / 32, 256, 0, stream>>>(value, mask, pkb, rem, outp);
}

// Round 14
// 162.394 us; speedup vs baseline: 1.0142x; 1.0110x over previous
//
#include <hip/hip_runtime.h>
#include <math.h>

// Problem: B=16, LQ=1024, LK=1024, DK=256, DV=256, fp32 in/out, mask int32.
// Identity: softmax_k(q_s + k_s with mask) == mask-weighted softmax of k_s alone
// (q_s cancels; masked entries are exactly -1e9 -> weight 0). query never read.
// k_s ~ N(0,256) => softmax mass concentrates in top ~30-60 keys; chunk-0
// (top-64) provably terminates ~all rows (e_64 ~ e^-26 * Z << 1e-5 * Z).
//
// R1: counting-sort select. R2 (FAIL): scalar chains. R3-R7: per-row walks
// latency-bound (best R4 50us). R8 (FAIL): reg pipeline, occ 6%. R9/R11
// (44-46us): 4 rows/wave LDS walk + scalar-selected weights = best.
// R12 (52us): L2-direct walk worse. R13 (52us): 8-rows/wave stagger ->
//   VGPR 88, occ 12%: intra-wave pipelining fails three ways running.
// R14: R11 rebalanced for RESIDENCY. Same 64KB LDS (2 blocks/CU cap) but
//   1024-thr blocks -> 32 waves/CU ceiling instead of 16; 2 rows/wave keeps
//   grid at 512 (2 blocks/CU) and live mask state at 8 int4 (VGPR ~64).
//   Doubled resident waves = doubled outstanding-load pool for the mask
//   stream + more walk waves to hide the barrier drain. LDS walk traffic
//   doubles per row but LDS has 5x headroom.

#define NB     16
#define NL     1024     // LQ == LK
#define ND     256      // DK == DV
#define NBKT   128      // buckets of width 1.0 in log-space

// ---------------- Kernel A: ks[b,k] = dot(key[b,k,:], w) -----------------
__global__ __launch_bounds__(256)
void ks_kernel(const float* __restrict__ key, const float* __restrict__ w,
               float* __restrict__ ks) {
    int wid  = threadIdx.x >> 6;
    int lane = threadIdx.x & 63;
    int row  = blockIdx.x * 4 + wid;               // 0 .. NB*NL-1
    const float4* krow = (const float4*)(key + (size_t)row * ND);
    float4 kv = krow[lane];
    float4 wv = ((const float4*)w)[lane];
    float p = kv.x * wv.x + kv.y * wv.y + kv.z * wv.z + kv.w * wv.w;
    #pragma unroll
    for (int off = 32; off > 0; off >>= 1)
        p += __shfl_xor(p, off, 64);
    if (lane == 0) ks[row] = p;
}

// ------- Kernel B: per batch: max, e=exp(ks-m), counting sort by -------
// ------- bucket floor(m-v), exact suffix mass at chunk boundaries -------
// 256 threads (4 waves), 4 entries/thread. Order within a bucket arbitrary;
// attn breaks on the EXACT suffix mass rem[] of the actual gathered order.
__global__ __launch_bounds__(256)
void select_kernel(const float* __restrict__ ks,
                   float2* __restrict__ pk, float* __restrict__ rem) {
    __shared__ float se[NL];       // gathered e values (bucket order)
    __shared__ int   cnt[NBKT];    // histogram
    __shared__ int   cur[NBKT];    // scan -> scatter cursors
    __shared__ float wred[4];      // per-wave max
    __shared__ float csum[16];     // per-chunk sums
    const int b    = blockIdx.x;
    const int t    = threadIdx.x;
    const int lane = t & 63;
    const int wid  = t >> 6;
    const float* ksb = ks + b * NL;

    if (t < NBKT) cnt[t] = 0;

    // 4 entries per thread, coalesced (stride 256)
    float v0 = ksb[t], v1 = ksb[t + 256], v2 = ksb[t + 512], v3 = ksb[t + 768];

    // block max: thread max4 -> wave shuffle reduce -> 4-way LDS combine
    float mx = fmaxf(fmaxf(v0, v1), fmaxf(v2, v3));
    #pragma unroll
    for (int off = 32; off > 0; off >>= 1)
        mx = fmaxf(mx, __shfl_xor(mx, off, 64));
    if (lane == 0) wred[wid] = mx;
    __syncthreads();                                        // #1 (also covers cnt=0)
    const float m = fmaxf(fmaxf(wred[0], wred[1]), fmaxf(wred[2], wred[3]));

    float e0 = __expf(v0 - m), e1 = __expf(v1 - m);
    float e2 = __expf(v2 - m), e3 = __expf(v3 - m);
    int b0 = (int)fminf(m - v0, (float)(NBKT - 1));
    int b1 = (int)fminf(m - v1, (float)(NBKT - 1));
    int b2 = (int)fminf(m - v2, (float)(NBKT - 1));
    int b3 = (int)fminf(m - v3, (float)(NBKT - 1));
    atomicAdd(&cnt[b0], 1); atomicAdd(&cnt[b1], 1);
    atomicAdd(&cnt[b2], 1); atomicAdd(&cnt[b3], 1);
    __syncthreads();                                        // #2

    // exclusive scan of cnt[128] by wave 0 via shuffles (no barriers inside)
    if (wid == 0) {
        int a  = cnt[lane];
        int b2v = cnt[lane + 64];
        int sa = a, sb = b2v;
        #pragma unroll
        for (int d = 1; d < 64; d <<= 1) {
            int na = __shfl_up(sa, d, 64);
            int nb = __shfl_up(sb, d, 64);
            if (lane >= d) { sa += na; sb += nb; }
        }
        int tot = __shfl(sa, 63, 64);
        sb += tot;
        cur[lane]      = sa - a;
        cur[lane + 64] = sb - b2v;
    }
    __syncthreads();                                        // #3

    // scatter (bijective: every entry gets a unique p in [0, NL))
    int p0 = atomicAdd(&cur[b0], 1);
    int p1 = atomicAdd(&cur[b1], 1);
    int p2 = atomicAdd(&cur[b2], 1);
    int p3 = atomicAdd(&cur[b3], 1);
    se[p0] = e0; pk[b * NL + p0] = make_float2(e0, __int_as_float(t));
    se[p1] = e1; pk[b * NL + p1] = make_float2(e1, __int_as_float(t + 256));
    se[p2] = e2; pk[b * NL + p2] = make_float2(e2, __int_as_float(t + 512));
    se[p3] = e3; pk[b * NL + p3] = make_float2(e3, __int_as_float(t + 768));
    __syncthreads();                                        // #4

    // per-chunk sums: wave w reduces chunks 4w..4w+3
    #pragma unroll
    for (int cc = 0; cc < 4; ++cc) {
        int chunk = wid * 4 + cc;
        float s = se[chunk * 64 + lane];
        #pragma unroll
        for (int off = 32; off > 0; off >>= 1)
            s += __shfl_xor(s, off, 64);
        if (lane == 0) csum[chunk] = s;
    }
    __syncthreads();                                        // #5

    // suffix masses at the 16 boundary slots attn actually reads
    if (t == 0) {
        float run = 0.0f;
        for (int c = 15; c >= 0; --c) {
            rem[b * NL + c * 64 + 63] = run;
            run += csum[c];
        }
    }
}

// ---------------- Kernel C: out[b,q,:] = sum_k p * value[b,k,:] ----------
// 1024 threads = 16 waves; ONE WAVE = 2 ROWS; block = 32 rows; grid 512;
// 64KB LDS (top-64 V rows) -> 2 blocks/CU x 16 waves = 32 waves/CU ceiling.
// Per wave: 8 coalesced int4 mask loads (R6 pattern) + pk float2 + 4 uniform
// V-stage loads; bits -> bpermute -> ballot -> butterfly Z per row; barrier;
// fixed-64 LDS walk, one ds_read_b128 feeds 2 accumulators, weights
// scalar-selected from SGPR ballot masks.
__global__ __launch_bounds__(1024)
void attn_kernel(const float* __restrict__ value, const int* __restrict__ mask,
                 const float2* __restrict__ pk, const float* __restrict__ rem,
                 float* __restrict__ out) {
    __shared__ float lds_V[64 * ND];          // 64 KB: top-64 value rows

    const int wid  = threadIdx.x >> 6;        // 0..15
    const int lane = threadIdx.x & 63;
    const int row0 = blockIdx.x * 32 + wid * 2;   // wave's 2 rows
    const int b    = row0 >> 10;
    const int base = b << 10;

    const float4* vbase = (const float4*)(value + ((size_t)b << 10) * ND);
    const float2* pk_g  = pk + base;

    // ---- prologue: issue all independent global loads first ----
    // mask rows, fully coalesced: load j covers columns 256j + 4*lane + (0..3)
    const int4* mr0 = (const int4*)(mask + (size_t)(row0 + 0) * NL);
    const int4* mr1 = (const int4*)(mask + (size_t)(row0 + 1) * NL);
    int4 a00 = mr0[lane], a01 = mr0[lane + 64], a02 = mr0[lane + 128], a03 = mr0[lane + 192];
    int4 a10 = mr1[lane], a11 = mr1[lane + 64], a12 = mr1[lane + 128], a13 = mr1[lane + 192];

    // top-64 metadata, lane-parallel (shared by all rows of the batch)
    float2 p0 = pk_g[lane];
    int   k0  = __float_as_int(p0.y);
    float e0  = p0.x;
    int   e0i = __float_as_int(e0);

    // stage top-64 V rows: wave w stages slots 4w..4w+3 (coalesced 1KB each)
    #pragma unroll
    for (int j = 0; j < 4; ++j) {
        int s   = wid * 4 + j;
        int ksr = __builtin_amdgcn_readlane(k0, s);    // uniform -> SGPR base
        ((float4*)lds_V)[s * 64 + lane] = vbase[(size_t)ksr * 64 + lane];
    }

    // ---- bits per row: bit (4j + c) = column 256j + 4*lane + c ----
    auto mkbits = [](int4 x0, int4 x1, int4 x2, int4 x3) -> unsigned int {
        unsigned int bits = 0;
        bits |= (x0.x != 0 ? 1u : 0u) << 0;  bits |= (x0.y != 0 ? 1u : 0u) << 1;
        bits |= (x0.z != 0 ? 1u : 0u) << 2;  bits |= (x0.w != 0 ? 1u : 0u) << 3;
        bits |= (x1.x != 0 ? 1u : 0u) << 4;  bits |= (x1.y != 0 ? 1u : 0u) << 5;
        bits |= (x1.z != 0 ? 1u : 0u) << 6;  bits |= (x1.w != 0 ? 1u : 0u) << 7;
        bits |= (x2.x != 0 ? 1u : 0u) << 8;  bits |= (x2.y != 0 ? 1u : 0u) << 9;
        bits |= (x2.z != 0 ? 1u : 0u) << 10; bits |= (x2.w != 0 ? 1u : 0u) << 11;
        bits |= (x3.x != 0 ? 1u : 0u) << 12; bits |= (x3.y != 0 ? 1u : 0u) << 13;
        bits |= (x3.z != 0 ? 1u : 0u) << 14; bits |= (x3.w != 0 ? 1u : 0u) << 15;
        return bits;
    };
    unsigned int bits0 = mkbits(a00, a01, a02, a03);
    unsigned int bits1 = mkbits(a10, a11, a12, a13);

    // bit for column k0: lane (k0>>2)&63, bit (k0&3) + 4*(k0>>8)  (R6 mapping)
    const int addr  = ((k0 >> 2) & 63) << 2;
    const int shift = (k0 & 3) + ((k0 >> 8) << 2);
    bool mb0 = (((unsigned int)__builtin_amdgcn_ds_bpermute(addr, (int)bits0)) >> shift) & 1u;
    bool mb1 = (((unsigned int)__builtin_amdgcn_ds_bpermute(addr, (int)bits1)) >> shift) & 1u;
    unsigned long long bm0 = __ballot(mb0);
    unsigned long long bm1 = __ballot(mb1);

    // Z per row: butterfly of mask-selected e (uniform result)
    auto zsum = [&](bool mb) -> float {
        float wz = mb ? e0 : 0.0f;
        #pragma unroll
        for (int off = 32; off > 0; off >>= 1)
            wz += __shfl_xor(wz, off, 64);
        return wz;
    };
    float z0 = zsum(mb0), z1 = zsum(mb1);

    __syncthreads();   // lds_V ready

    // ---- walk: fixed 64 iterations over LDS; weights scalar-selected ----
    float4 acc0 = make_float4(0.f, 0.f, 0.f, 0.f);
    float4 acc1 = make_float4(0.f, 0.f, 0.f, 0.f);

    #pragma unroll 16
    for (int i = 0; i < 64; ++i) {
        float4 v = ((const float4*)lds_V)[i * 64 + lane];
        float ei = __int_as_float(__builtin_amdgcn_readlane(e0i, i));
        float w0 = ((bm0 >> i) & 1ull) ? ei : 0.0f;      // s_cselect
        float w1 = ((bm1 >> i) & 1ull) ? ei : 0.0f;
        acc0.x += w0 * v.x; acc0.y += w0 * v.y; acc0.z += w0 * v.z; acc0.w += w0 * v.w;
        acc1.x += w1 * v.x; acc1.y += w1 * v.y; acc1.z += w1 * v.z; acc1.w += w1 * v.w;
    }

    // ---- per-row epilogue: done check, rare deep chunks, store ----
    const float remv = rem[base + 63];

    auto finish_row = [&](int r, float4 acc, float Z) {
        const int* mrow = mask + (size_t)(row0 + r) * NL;
        bool done = (remv <= 1e-5f * Z);     // Z==0 -> rem>0 -> continue
        for (int c = 1; c < 16 && !done; ++c) {           // ~never taken
            float2 p = pk_g[c * 64 + lane];
            float e  = p.x;
            int   k  = __float_as_int(p.y);
            bool mb  = (mrow[k] != 0);
            float dz = mb ? e : 0.0f;
            #pragma unroll
            for (int off = 32; off > 0; off >>= 1)
                dz += __shfl_xor(dz, off, 64);
            unsigned long long bmx = __ballot(mb);
            int eI = __float_as_int(e);
            for (int i = 0; i < 64; ++i) {                // rolled: rare path
                float ei = __int_as_float(__builtin_amdgcn_readlane(eI, i));
                int   ki = __builtin_amdgcn_readlane(k, i);
                float w  = ((bmx >> i) & 1ull) ? ei : 0.0f;
                float4 v = vbase[(size_t)ki * 64 + lane];
                acc.x += w * v.x; acc.y += w * v.y;
                acc.z += w * v.z; acc.w += w * v.w;
            }
            Z += dz;
            done = (rem[base + c * 64 + 63] <= 1e-5f * Z);
        }
        float4* orow = (float4*)(out + (size_t)(row0 + r) * ND);
        if (Z > 0.0f) {
            float inv = 1.0f / Z;
            orow[lane] = make_float4(acc.x * inv, acc.y * inv,
                                     acc.z * inv, acc.w * inv);
        } else {
            // all-masked row: softmax over constant -1e9 -> uniform average
            float4 s = make_float4(0.f, 0.f, 0.f, 0.f);
            for (int k = 0; k < NL; ++k) {
                float4 v = vbase[(size_t)k * 64 + lane];
                s.x += v.x; s.y += v.y; s.z += v.z; s.w += v.w;
            }
            const float inv = 1.0f / (float)NL;
            orow[lane] = make_float4(s.x * inv, s.y * inv, s.z * inv, s.w * inv);
        }
    };
    finish_row(0, acc0, z0);
    finish_row(1, acc1, z1);
}

extern "C" void kernel_launch(void* const* d_in, const int* in_sizes, int n_in,
                              void* d_out, int out_size, void* d_ws, size_t ws_size,
                              hipStream_t stream) {
    // setup_inputs order: query, key, value, w, mask   (query unused!)
    const float* key   = (const float*)d_in[1];
    const float* value = (const float*)d_in[2];
    const float* w     = (const float*)d_in[3];
    const int*   mask  = (const int*)d_in[4];
    float*       outp  = (float*)d_out;

    float*  ks  = (float*)d_ws;                  // 16*1024 f32
    float2* pkb = (float2*)(ks + NB * NL);       // 16*1024 f32x2 (e, idx) bucket-desc
    float*  rem = (float*)(pkb + NB * NL);       // 16*1024 f32 suffix masses

    ks_kernel    <<<NB * NL / 4, 256, 0, stream>>>(key, w, ks);
    select_kernel<<<NB, 256, 0, stream>>>(ks, pkb, rem);
    attn_kernel  <<<NB * NL / 32, 1024, 0, stream>>>(value, mask, pkb, rem, outp);
}

// Round 15
// 161.095 us; speedup vs baseline: 1.0224x; 1.0081x over previous
//
#include <hip/hip_runtime.h>
#include <math.h>

// Problem: B=16, LQ=1024, LK=1024, DK=256, DV=256, fp32 in/out, mask int32.
// Identity: softmax_k(q_s + k_s with mask) == mask-weighted softmax of k_s alone
// (q_s cancels; masked entries are exactly -1e9 -> weight 0). query never read.
// k_s ~ N(0,256) => softmax mass concentrates in top ~30-60 keys; chunk-0
// (top-64) provably terminates ~all rows (e_64 ~ e^-26 * Z << 1e-5 * Z).
//
// R1-R14 history: counting-sort select (R1); per-row walks latency-bound
// (R3-R7, best R4 50us); reg pipelines kill occupancy (R8, R13); LDS walk
// with scalar-selected weights = best core (R9/R11, 44-46us); L2-direct walk
// worse (R12); occupancy NOT the limiter (R14: occ 22->30%, attn 45->53).
// Invariant across all: the 64MB mask read sits in a kernel that can't
// stream it (1.1-1.3 TB/s vs fills' 6.6).
// R15: mask COMPRESSION (mask row -> 64 u16 words, 128B/row, 2MB table)
// fused into ks_kernel -- compression needs NO pk, so no extra launch and
// no dependency (R10's mistake). ks_kernel is already a pure streamer; it
// now carries key(16.7MB)+mask(64MB) at streaming BW. attn replaces its
// 16 int4 mask loads + bit-build + bpermute with FOUR 2B gathers from the
// L2/L3-hot table (same R6 bit mapping: word=(k>>2)&63, bit=(k&3)+4*(k>>8)).
// attn keeps the proven R11 shape: 512thr, 4 rows/wave, 64KB LDS walk.

#define NB     16
#define NL     1024     // LQ == LK
#define ND     256      // DK == DV
#define NBKT   128      // buckets of width 1.0 in log-space

// ---- Kernel A: ks[b,k] = dot(key[b,k,:], w)  +  mask-row bit compression ----
// 4 waves/block, 1 row/wave, grid 4096. Pure streamer: key 16.7MB + mask
// 64MB coalesced reads, 2MB bit-table + 64KB ks writes. No LDS, no barriers.
__global__ __launch_bounds__(256)
void ksm_kernel(const float* __restrict__ key, const float* __restrict__ w,
                const int* __restrict__ mask,
                float* __restrict__ ks, unsigned short* __restrict__ bmtab) {
    int wid  = threadIdx.x >> 6;
    int lane = threadIdx.x & 63;
    int row  = blockIdx.x * 4 + wid;               // 0 .. NB*NL-1

    // independent loads, all issued up front
    const float4* krow = (const float4*)(key + (size_t)row * ND);
    float4 kv = krow[lane];
    float4 wv = ((const float4*)w)[lane];
    const int4* mrow4 = (const int4*)(mask + (size_t)row * NL);
    int4 m0 = mrow4[lane], m1 = mrow4[lane + 64];
    int4 m2 = mrow4[lane + 128], m3 = mrow4[lane + 192];

    // key dot -> wave reduce
    float p = kv.x * wv.x + kv.y * wv.y + kv.z * wv.z + kv.w * wv.w;
    #pragma unroll
    for (int off = 32; off > 0; off >>= 1)
        p += __shfl_xor(p, off, 64);

    // mask bits: bit (4j + c) of lane L's word = (mask[row][256j+4L+c] != 0)
    unsigned int bits = 0;
    bits |= (m0.x != 0 ? 1u : 0u) << 0;  bits |= (m0.y != 0 ? 1u : 0u) << 1;
    bits |= (m0.z != 0 ? 1u : 0u) << 2;  bits |= (m0.w != 0 ? 1u : 0u) << 3;
    bits |= (m1.x != 0 ? 1u : 0u) << 4;  bits |= (m1.y != 0 ? 1u : 0u) << 5;
    bits |= (m1.z != 0 ? 1u : 0u) << 6;  bits |= (m1.w != 0 ? 1u : 0u) << 7;
    bits |= (m2.x != 0 ? 1u : 0u) << 8;  bits |= (m2.y != 0 ? 1u : 0u) << 9;
    bits |= (m2.z != 0 ? 1u : 0u) << 10; bits |= (m2.w != 0 ? 1u : 0u) << 11;
    bits |= (m3.x != 0 ? 1u : 0u) << 12; bits |= (m3.y != 0 ? 1u : 0u) << 13;
    bits |= (m3.z != 0 ? 1u : 0u) << 14; bits |= (m3.w != 0 ? 1u : 0u) << 15;

    bmtab[(size_t)row * 64 + lane] = (unsigned short)bits;   // 128B/row coalesced
    if (lane == 0) ks[row] = p;
}

// ------- Kernel B: per batch: max, e=exp(ks-m), counting sort by -------
// ------- bucket floor(m-v), exact suffix mass at chunk boundaries -------
// 256 threads (4 waves), 4 entries/thread. Order within a bucket arbitrary;
// attn breaks on the EXACT suffix mass rem[] of the actual gathered order.
__global__ __launch_bounds__(256)
void select_kernel(const float* __restrict__ ks,
                   float2* __restrict__ pk, float* __restrict__ rem) {
    __shared__ float se[NL];       // gathered e values (bucket order)
    __shared__ int   cnt[NBKT];    // histogram
    __shared__ int   cur[NBKT];    // scan -> scatter cursors
    __shared__ float wred[4];      // per-wave max
    __shared__ float csum[16];     // per-chunk sums
    const int b    = blockIdx.x;
    const int t    = threadIdx.x;
    const int lane = t & 63;
    const int wid  = t >> 6;
    const float* ksb = ks + b * NL;

    if (t < NBKT) cnt[t] = 0;

    // 4 entries per thread, coalesced (stride 256)
    float v0 = ksb[t], v1 = ksb[t + 256], v2 = ksb[t + 512], v3 = ksb[t + 768];

    // block max: thread max4 -> wave shuffle reduce -> 4-way LDS combine
    float mx = fmaxf(fmaxf(v0, v1), fmaxf(v2, v3));
    #pragma unroll
    for (int off = 32; off > 0; off >>= 1)
        mx = fmaxf(mx, __shfl_xor(mx, off, 64));
    if (lane == 0) wred[wid] = mx;
    __syncthreads();                                        // #1 (also covers cnt=0)
    const float m = fmaxf(fmaxf(wred[0], wred[1]), fmaxf(wred[2], wred[3]));

    float e0 = __expf(v0 - m), e1 = __expf(v1 - m);
    float e2 = __expf(v2 - m), e3 = __expf(v3 - m);
    int b0 = (int)fminf(m - v0, (float)(NBKT - 1));
    int b1 = (int)fminf(m - v1, (float)(NBKT - 1));
    int b2 = (int)fminf(m - v2, (float)(NBKT - 1));
    int b3 = (int)fminf(m - v3, (float)(NBKT - 1));
    atomicAdd(&cnt[b0], 1); atomicAdd(&cnt[b1], 1);
    atomicAdd(&cnt[b2], 1); atomicAdd(&cnt[b3], 1);
    __syncthreads();                                        // #2

    // exclusive scan of cnt[128] by wave 0 via shuffles (no barriers inside)
    if (wid == 0) {
        int a  = cnt[lane];
        int b2v = cnt[lane + 64];
        int sa = a, sb = b2v;
        #pragma unroll
        for (int d = 1; d < 64; d <<= 1) {
            int na = __shfl_up(sa, d, 64);
            int nb = __shfl_up(sb, d, 64);
            if (lane >= d) { sa += na; sb += nb; }
        }
        int tot = __shfl(sa, 63, 64);
        sb += tot;
        cur[lane]      = sa - a;
        cur[lane + 64] = sb - b2v;
    }
    __syncthreads();                                        // #3

    // scatter (bijective: every entry gets a unique p in [0, NL))
    int p0 = atomicAdd(&cur[b0], 1);
    int p1 = atomicAdd(&cur[b1], 1);
    int p2 = atomicAdd(&cur[b2], 1);
    int p3 = atomicAdd(&cur[b3], 1);
    se[p0] = e0; pk[b * NL + p0] = make_float2(e0, __int_as_float(t));
    se[p1] = e1; pk[b * NL + p1] = make_float2(e1, __int_as_float(t + 256));
    se[p2] = e2; pk[b * NL + p2] = make_float2(e2, __int_as_float(t + 512));
    se[p3] = e3; pk[b * NL + p3] = make_float2(e3, __int_as_float(t + 768));
    __syncthreads();                                        // #4

    // per-chunk sums: wave w reduces chunks 4w..4w+3
    #pragma unroll
    for (int cc = 0; cc < 4; ++cc) {
        int chunk = wid * 4 + cc;
        float s = se[chunk * 64 + lane];
        #pragma unroll
        for (int off = 32; off > 0; off >>= 1)
            s += __shfl_xor(s, off, 64);
        if (lane == 0) csum[chunk] = s;
    }
    __syncthreads();                                        // #5

    // suffix masses at the 16 boundary slots attn actually reads
    if (t == 0) {
        float run = 0.0f;
        for (int c = 15; c >= 0; --c) {
            rem[b * NL + c * 64 + 63] = run;
            run += csum[c];
        }
    }
}

// ---------------- Kernel C: out[b,q,:] = sum_k p * value[b,k,:] ----------
// 512 threads = 8 waves; ONE WAVE = 4 ROWS of one batch; block = 32 rows;
// grid 512; 64KB LDS (top-64 V rows). Mask resolved by FOUR 2B gathers from
// the precompressed bit table (L2/L3-hot, 128B/row) -- no 64MB stream here.
// Walk = fixed 64 iters: one ds_read_b128 feeds 4 accumulators, weights
// scalar-selected from SGPR ballot masks (R11 walk, unchanged).
__global__ __launch_bounds__(512)
void attn_kernel(const float* __restrict__ value, const int* __restrict__ mask,
                 const float2* __restrict__ pk, const float* __restrict__ rem,
                 const unsigned short* __restrict__ bmtab,
                 float* __restrict__ out) {
    __shared__ float lds_V[64 * ND];          // 64 KB: top-64 value rows

    const int wid  = threadIdx.x >> 6;        // 0..7
    const int lane = threadIdx.x & 63;
    const int row0 = blockIdx.x * 32 + wid * 4;   // wave's 4 rows
    const int b    = row0 >> 10;
    const int base = b << 10;

    const float4* vbase = (const float4*)(value + ((size_t)b << 10) * ND);
    const float2* pk_g  = pk + base;

    // top-64 metadata, lane-parallel (shared by all rows of the batch)
    float2 p0 = pk_g[lane];
    int   k0  = __float_as_int(p0.y);
    float e0  = p0.x;
    int   e0i = __float_as_int(e0);

    // bit for column k0 lives in word (k0>>2)&63, bit (k0&3)+4*(k0>>8)
    const int L     = (k0 >> 2) & 63;
    const int shift = (k0 & 3) + ((k0 >> 8) << 2);

    // 4 independent 2B gathers (128B/row table rows, L2/L3-hot), issued first
    unsigned short t0 = bmtab[(size_t)(row0 + 0) * 64 + L];
    unsigned short t1 = bmtab[(size_t)(row0 + 1) * 64 + L];
    unsigned short t2 = bmtab[(size_t)(row0 + 2) * 64 + L];
    unsigned short t3 = bmtab[(size_t)(row0 + 3) * 64 + L];

    // stage top-64 V rows: wave w stages slots 8w..8w+7 (coalesced 1KB each)
    #pragma unroll
    for (int j = 0; j < 8; ++j) {
        int s   = wid * 8 + j;
        int ksr = __builtin_amdgcn_readlane(k0, s);    // uniform -> SGPR base
        ((float4*)lds_V)[s * 64 + lane] = vbase[(size_t)ksr * 64 + lane];
    }

    bool mb0 = (t0 >> shift) & 1;
    bool mb1 = (t1 >> shift) & 1;
    bool mb2 = (t2 >> shift) & 1;
    bool mb3 = (t3 >> shift) & 1;
    unsigned long long bm0 = __ballot(mb0);
    unsigned long long bm1 = __ballot(mb1);
    unsigned long long bm2 = __ballot(mb2);
    unsigned long long bm3 = __ballot(mb3);

    // Z per row: butterfly of mask-selected e (uniform result)
    auto zsum = [&](bool mb) -> float {
        float wz = mb ? e0 : 0.0f;
        #pragma unroll
        for (int off = 32; off > 0; off >>= 1)
            wz += __shfl_xor(wz, off, 64);
        return wz;
    };
    float z0 = zsum(mb0), z1 = zsum(mb1), z2 = zsum(mb2), z3 = zsum(mb3);

    __syncthreads();   // lds_V ready

    // ---- walk: fixed 64 iterations over LDS; weights scalar-selected ----
    float4 acc0 = make_float4(0.f, 0.f, 0.f, 0.f);
    float4 acc1 = make_float4(0.f, 0.f, 0.f, 0.f);
    float4 acc2 = make_float4(0.f, 0.f, 0.f, 0.f);
    float4 acc3 = make_float4(0.f, 0.f, 0.f, 0.f);

    #pragma unroll 16
    for (int i = 0; i < 64; ++i) {
        float4 v = ((const float4*)lds_V)[i * 64 + lane];
        float ei = __int_as_float(__builtin_amdgcn_readlane(e0i, i));
        float w0 = ((bm0 >> i) & 1ull) ? ei : 0.0f;      // s_cselect
        float w1 = ((bm1 >> i) & 1ull) ? ei : 0.0f;
        float w2 = ((bm2 >> i) & 1ull) ? ei : 0.0f;
        float w3 = ((bm3 >> i) & 1ull) ? ei : 0.0f;
        acc0.x += w0 * v.x; acc0.y += w0 * v.y; acc0.z += w0 * v.z; acc0.w += w0 * v.w;
        acc1.x += w1 * v.x; acc1.y += w1 * v.y; acc1.z += w1 * v.z; acc1.w += w1 * v.w;
        acc2.x += w2 * v.x; acc2.y += w2 * v.y; acc2.z += w2 * v.z; acc2.w += w2 * v.w;
        acc3.x += w3 * v.x; acc3.y += w3 * v.y; acc3.z += w3 * v.z; acc3.w += w3 * v.w;
    }

    // ---- per-row epilogue: done check, rare deep chunks, store ----
    const float remv = rem[base + 63];

    auto finish_row = [&](int r, float4 acc, float Z) {
        const int* mrow = mask + (size_t)(row0 + r) * NL;
        bool done = (remv <= 1e-5f * Z);     // Z==0 -> rem>0 -> continue
        for (int c = 1; c < 16 && !done; ++c) {           // ~never taken
            float2 p = pk_g[c * 64 + lane];
            float e  = p.x;
            int   k  = __float_as_int(p.y);
            bool mb  = (mrow[k] != 0);
            float dz = mb ? e : 0.0f;
            #pragma unroll
            for (int off = 32; off > 0; off >>= 1)
                dz += __shfl_xor(dz, off, 64);
            unsigned long long bmx = __ballot(mb);
            int eI = __float_as_int(e);
            for (int i = 0; i < 64; ++i) {                // rolled: rare path
                float ei = __int_as_float(__builtin_amdgcn_readlane(eI, i));
                int   ki = __builtin_amdgcn_readlane(k, i);
                float w  = ((bmx >> i) & 1ull) ? ei : 0.0f;
                float4 v = vbase[(size_t)ki * 64 + lane];
                acc.x += w * v.x; acc.y += w * v.y;
                acc.z += w * v.z; acc.w += w * v.w;
            }
            Z += dz;
            done = (rem[base + c * 64 + 63] <= 1e-5f * Z);
        }
        float4* orow = (float4*)(out + (size_t)(row0 + r) * ND);
        if (Z > 0.0f) {
            float inv = 1.0f / Z;
            orow[lane] = make_float4(acc.x * inv, acc.y * inv,
                                     acc.z * inv, acc.w * inv);
        } else {
            // all-masked row: softmax over constant -1e9 -> uniform average
            float4 s = make_float4(0.f, 0.f, 0.f, 0.f);
            for (int k = 0; k < NL; ++k) {
                float4 v = vbase[(size_t)k * 64 + lane];
                s.x += v.x; s.y += v.y; s.z += v.z; s.w += v.w;
            }
            const float inv = 1.0f / (float)NL;
            orow[lane] = make_float4(s.x * inv, s.y * inv, s.z * inv, s.w * inv);
        }
    };
    finish_row(0, acc0, z0);
    finish_row(1, acc1, z1);
    finish_row(2, acc2, z2);
    finish_row(3, acc3, z3);
}

extern "C" void kernel_launch(void* const* d_in, const int* in_sizes, int n_in,
                              void* d_out, int out_size, void* d_ws, size_t ws_size,
                              hipStream_t stream) {
    // setup_inputs order: query, key, value, w, mask   (query unused!)
    const float* key   = (const float*)d_in[1];
    const float* value = (const float*)d_in[2];
    const float* w     = (const float*)d_in[3];
    const int*   mask  = (const int*)d_in[4];
    float*       outp  = (float*)d_out;

    float*  ks  = (float*)d_ws;                  // 16*1024 f32
    float2* pkb = (float2*)(ks + NB * NL);       // 16*1024 f32x2 (e, idx) bucket-desc
    float*  rem = (float*)(pkb + NB * NL);       // 16*1024 f32 suffix masses
    unsigned short* bmtab =
        (unsigned short*)(rem + NB * NL);        // 16*1024 x 64 u16 bit table (2MB)

    ksm_kernel   <<<NB * NL / 4, 256, 0, stream>>>(key, w, mask, ks, bmtab);
    select_kernel<<<NB, 256, 0, stream>>>(ks, pkb, rem);
    attn_kernel  <<<NB * NL / 32, 512, 0, stream>>>(value, mask, pkb, rem,
                                                    bmtab, outp);
}

// Round 16
// 157.950 us; speedup vs baseline: 1.0428x; 1.0199x over previous
//
#include <hip/hip_runtime.h>
#include <math.h>

// Problem: B=16, LQ=1024, LK=1024, DK=256, DV=256, fp32 in/out, mask int32.
// Identity: softmax_k(q_s + k_s with mask) == mask-weighted softmax of k_s alone
// (q_s cancels; masked entries are exactly -1e9 -> weight 0). query never read.
// k_s ~ N(0,256) => softmax mass concentrates in top ~30-60 keys; chunk-0
// (top-64) provably terminates ~all rows (e_64 ~ e^-26 * Z << 1e-5 * Z).
//
// R1-R15 summary: best attn core = LDS-staged top-64 V walk, 4 rows/wave,
// weights scalar-selected from SGPR ballot masks (R11). Mask stream belongs
// in a pure streamer (R15: fused into ks kernel as a 2MB bit table). All
// kernels now < the 40us harness fills; remaining slack = chain + gaps.
// R16: select FUSED into attn. Each attn block re-derives its batch's
// bucket-sort locally from ks (4KB, L2-hot; any per-block order with exact
// suffix masses is correct -- R1 argument). Chain: ksm -> attn (2 kernels).
// Removes 1 launch + 1 gap + pk/rem round-trip; pk lives in LDS.

#define NB     16
#define NL     1024     // LQ == LK
#define ND     256      // DK == DV
#define NBKT   128      // buckets of width 1.0 in log-space

// ---- Kernel A: ks[b,k] = dot(key[b,k,:], w)  +  mask-row bit compression ----
// 4 waves/block, 1 row/wave, grid 4096. Pure streamer: key 16.7MB + mask
// 64MB coalesced reads, 2MB bit-table + 64KB ks writes. No LDS, no barriers.
__global__ __launch_bounds__(256)
void ksm_kernel(const float* __restrict__ key, const float* __restrict__ w,
                const int* __restrict__ mask,
                float* __restrict__ ks, unsigned short* __restrict__ bmtab) {
    int wid  = threadIdx.x >> 6;
    int lane = threadIdx.x & 63;
    int row  = blockIdx.x * 4 + wid;               // 0 .. NB*NL-1

    // independent loads, all issued up front
    const float4* krow = (const float4*)(key + (size_t)row * ND);
    float4 kv = krow[lane];
    float4 wv = ((const float4*)w)[lane];
    const int4* mrow4 = (const int4*)(mask + (size_t)row * NL);
    int4 m0 = mrow4[lane], m1 = mrow4[lane + 64];
    int4 m2 = mrow4[lane + 128], m3 = mrow4[lane + 192];

    // key dot -> wave reduce
    float p = kv.x * wv.x + kv.y * wv.y + kv.z * wv.z + kv.w * wv.w;
    #pragma unroll
    for (int off = 32; off > 0; off >>= 1)
        p += __shfl_xor(p, off, 64);

    // mask bits: bit (4j + c) of lane L's word = (mask[row][256j+4L+c] != 0)
    unsigned int bits = 0;
    bits |= (m0.x != 0 ? 1u : 0u) << 0;  bits |= (m0.y != 0 ? 1u : 0u) << 1;
    bits |= (m0.z != 0 ? 1u : 0u) << 2;  bits |= (m0.w != 0 ? 1u : 0u) << 3;
    bits |= (m1.x != 0 ? 1u : 0u) << 4;  bits |= (m1.y != 0 ? 1u : 0u) << 5;
    bits |= (m1.z != 0 ? 1u : 0u) << 6;  bits |= (m1.w != 0 ? 1u : 0u) << 7;
    bits |= (m2.x != 0 ? 1u : 0u) << 8;  bits |= (m2.y != 0 ? 1u : 0u) << 9;
    bits |= (m2.z != 0 ? 1u : 0u) << 10; bits |= (m2.w != 0 ? 1u : 0u) << 11;
    bits |= (m3.x != 0 ? 1u : 0u) << 12; bits |= (m3.y != 0 ? 1u : 0u) << 13;
    bits |= (m3.z != 0 ? 1u : 0u) << 14; bits |= (m3.w != 0 ? 1u : 0u) << 15;

    bmtab[(size_t)row * 64 + lane] = (unsigned short)bits;   // 128B/row coalesced
    if (lane == 0) ks[row] = p;
}

// ---------------- Kernel B: fused select + attention ----------------
// 512 threads = 8 waves; block = 32 rows of one batch; grid 512.
// Phase 1 (local select): read batch ks (4KB, L2-hot), block max, e=exp,
//   counting-sort by bucket floor(m-v) into LDS pk_lds (e, idx), per-chunk
//   sums csum[16]. Any per-block order is valid: the walk processes whole
//   chunks and breaks on the EXACT suffix mass of THIS block's order.
// Phase 2 (walk): top-64 V rows staged in LDS; ONE WAVE = 4 ROWS; mask bits
//   from the precompressed table (4x 2B gathers); fixed-64 LDS walk with
//   scalar-selected weights (R11 core, unchanged).
__global__ __launch_bounds__(512)
void attn_kernel(const float* __restrict__ value, const int* __restrict__ mask,
                 const float* __restrict__ ks,
                 const unsigned short* __restrict__ bmtab,
                 float* __restrict__ out) {
    __shared__ float  lds_V[64 * ND];   // 64 KB: top-64 value rows
    __shared__ float2 pk_lds[NL];       // 8 KB: (e, idx) bucket-desc order
    __shared__ int    cnt[NBKT];        // histogram
    __shared__ int    cur[NBKT];        // scan -> scatter cursors
    __shared__ float  wred[8];          // per-wave max
    __shared__ float  csum[16];         // per-chunk sums

    const int t    = threadIdx.x;       // 0..511
    const int wid  = t >> 6;            // 0..7
    const int lane = t & 63;
    const int row0 = blockIdx.x * 32 + wid * 4;   // wave's 4 rows
    const int b    = row0 >> 10;

    const float4* vbase = (const float4*)(value + ((size_t)b << 10) * ND);
    const float*  ksb   = ks + b * NL;

    // ================= phase 1: local select =================
    if (t < NBKT) cnt[t] = 0;

    // 2 entries per thread, coalesced (stride 512)
    float v0 = ksb[t], v1 = ksb[t + 512];

    // block max: thread max2 -> wave shuffle reduce -> 8-way LDS combine
    float mx = fmaxf(v0, v1);
    #pragma unroll
    for (int off = 32; off > 0; off >>= 1)
        mx = fmaxf(mx, __shfl_xor(mx, off, 64));
    if (lane == 0) wred[wid] = mx;
    __syncthreads();                                        // #1 (covers cnt=0)
    float m = wred[0];
    #pragma unroll
    for (int j = 1; j < 8; ++j) m = fmaxf(m, wred[j]);

    float e0v = __expf(v0 - m), e1v = __expf(v1 - m);
    int b0 = (int)fminf(m - v0, (float)(NBKT - 1));         // m - v >= 0
    int b1 = (int)fminf(m - v1, (float)(NBKT - 1));
    atomicAdd(&cnt[b0], 1); atomicAdd(&cnt[b1], 1);
    __syncthreads();                                        // #2

    // exclusive scan of cnt[128] by wave 0 via shuffles
    if (wid == 0) {
        int a   = cnt[lane];
        int b2v = cnt[lane + 64];
        int sa = a, sb = b2v;
        #pragma unroll
        for (int d = 1; d < 64; d <<= 1) {
            int na = __shfl_up(sa, d, 64);
            int nb = __shfl_up(sb, d, 64);
            if (lane >= d) { sa += na; sb += nb; }
        }
        int tot = __shfl(sa, 63, 64);
        sb += tot;
        cur[lane]      = sa - a;
        cur[lane + 64] = sb - b2v;
    }
    __syncthreads();                                        // #3

    // scatter (bijective within the block)
    int p0i = atomicAdd(&cur[b0], 1);
    int p1i = atomicAdd(&cur[b1], 1);
    pk_lds[p0i] = make_float2(e0v, __int_as_float(t));
    pk_lds[p1i] = make_float2(e1v, __int_as_float(t + 512));
    __syncthreads();                                        // #4 (pk_lds ready)

    // per-chunk sums: wave w reduces chunks 2w, 2w+1
    #pragma unroll
    for (int cc = 0; cc < 2; ++cc) {
        int chunk = wid * 2 + cc;
        float s = pk_lds[chunk * 64 + lane].x;
        #pragma unroll
        for (int off = 32; off > 0; off >>= 1)
            s += __shfl_xor(s, off, 64);
        if (lane == 0) csum[chunk] = s;
    }

    // ================= phase 2: walk prep (overlaps csum) =================
    // top-64 metadata, lane-parallel (shared by all rows of the batch)
    float2 p0 = pk_lds[lane];
    int   k0  = __float_as_int(p0.y);
    float e0  = p0.x;
    int   e0i = __float_as_int(e0);

    // bit for column k0 lives in word (k0>>2)&63, bit (k0&3)+4*(k0>>8)
    const int L     = (k0 >> 2) & 63;
    const int shift = (k0 & 3) + ((k0 >> 8) << 2);

    // 4 independent 2B gathers (128B/row table rows, L2/L3-hot)
    unsigned short t0 = bmtab[(size_t)(row0 + 0) * 64 + L];
    unsigned short t1 = bmtab[(size_t)(row0 + 1) * 64 + L];
    unsigned short t2 = bmtab[(size_t)(row0 + 2) * 64 + L];
    unsigned short t3 = bmtab[(size_t)(row0 + 3) * 64 + L];

    // stage top-64 V rows: wave w stages slots 8w..8w+7 (coalesced 1KB each)
    #pragma unroll
    for (int j = 0; j < 8; ++j) {
        int s   = wid * 8 + j;
        int ksr = __builtin_amdgcn_readlane(k0, s);    // uniform -> SGPR base
        ((float4*)lds_V)[s * 64 + lane] = vbase[(size_t)ksr * 64 + lane];
    }

    bool mb0 = (t0 >> shift) & 1;
    bool mb1 = (t1 >> shift) & 1;
    bool mb2 = (t2 >> shift) & 1;
    bool mb3 = (t3 >> shift) & 1;
    unsigned long long bm0 = __ballot(mb0);
    unsigned long long bm1 = __ballot(mb1);
    unsigned long long bm2 = __ballot(mb2);
    unsigned long long bm3 = __ballot(mb3);

    // Z per row: butterfly of mask-selected e (uniform result)
    auto zsum = [&](bool mb) -> float {
        float wz = mb ? e0 : 0.0f;
        #pragma unroll
        for (int off = 32; off > 0; off >>= 1)
            wz += __shfl_xor(wz, off, 64);
        return wz;
    };
    float z0 = zsum(mb0), z1 = zsum(mb1), z2 = zsum(mb2), z3 = zsum(mb3);

    __syncthreads();   // #5: lds_V + csum ready

    // ---- walk: fixed 64 iterations over LDS; weights scalar-selected ----
    float4 acc0 = make_float4(0.f, 0.f, 0.f, 0.f);
    float4 acc1 = make_float4(0.f, 0.f, 0.f, 0.f);
    float4 acc2 = make_float4(0.f, 0.f, 0.f, 0.f);
    float4 acc3 = make_float4(0.f, 0.f, 0.f, 0.f);

    #pragma unroll 16
    for (int i = 0; i < 64; ++i) {
        float4 v = ((const float4*)lds_V)[i * 64 + lane];
        float ei = __int_as_float(__builtin_amdgcn_readlane(e0i, i));
        float w0 = ((bm0 >> i) & 1ull) ? ei : 0.0f;      // s_cselect
        float w1 = ((bm1 >> i) & 1ull) ? ei : 0.0f;
        float w2 = ((bm2 >> i) & 1ull) ? ei : 0.0f;
        float w3 = ((bm3 >> i) & 1ull) ? ei : 0.0f;
        acc0.x += w0 * v.x; acc0.y += w0 * v.y; acc0.z += w0 * v.z; acc0.w += w0 * v.w;
        acc1.x += w1 * v.x; acc1.y += w1 * v.y; acc1.z += w1 * v.z; acc1.w += w1 * v.w;
        acc2.x += w2 * v.x; acc2.y += w2 * v.y; acc2.z += w2 * v.z; acc2.w += w2 * v.w;
        acc3.x += w3 * v.x; acc3.y += w3 * v.y; acc3.z += w3 * v.z; acc3.w += w3 * v.w;
    }

    // suffix mass after chunk 0 = sum csum[1..15] (LDS reads, no reg array)
    float remA = 0.0f;
    #pragma unroll
    for (int j = 1; j < 16; ++j) remA += csum[j];

    // ---- per-row epilogue: done check, rare deep chunks, store ----
    auto finish_row = [&](int r, float4 acc, float Z) {
        const int* mrow = mask + (size_t)(row0 + r) * NL;
        float rsuf = remA;
        bool done = (rsuf <= 1e-5f * Z);     // Z==0 -> rem>0 -> continue
        for (int c = 1; c < 16 && !done; ++c) {           // ~never taken
            float2 p = pk_lds[c * 64 + lane];
            float e  = p.x;
            int   k  = __float_as_int(p.y);
            bool mb  = (mrow[k] != 0);
            float dz = mb ? e : 0.0f;
            #pragma unroll
            for (int off = 32; off > 0; off >>= 1)
                dz += __shfl_xor(dz, off, 64);
            unsigned long long bmx = __ballot(mb);
            int eI = __float_as_int(e);
            for (int i = 0; i < 64; ++i) {                // rolled: rare path
                float ei = __int_as_float(__builtin_amdgcn_readlane(eI, i));
                int   ki = __builtin_amdgcn_readlane(k, i);
                float w  = ((bmx >> i) & 1ull) ? ei : 0.0f;
                float4 v = vbase[(size_t)ki * 64 + lane];
                acc.x += w * v.x; acc.y += w * v.y;
                acc.z += w * v.z; acc.w += w * v.w;
            }
            Z += dz;
            rsuf -= csum[c];
            done = (rsuf <= 1e-5f * Z);
        }
        float4* orow = (float4*)(out + (size_t)(row0 + r) * ND);
        if (Z > 0.0f) {
            float inv = 1.0f / Z;
            orow[lane] = make_float4(acc.x * inv, acc.y * inv,
                                     acc.z * inv, acc.w * inv);
        } else {
            // all-masked row: softmax over constant -1e9 -> uniform average
            float4 s = make_float4(0.f, 0.f, 0.f, 0.f);
            for (int k = 0; k < NL; ++k) {
                float4 v = vbase[(size_t)k * 64 + lane];
                s.x += v.x; s.y += v.y; s.z += v.z; s.w += v.w;
            }
            const float inv = 1.0f / (float)NL;
            orow[lane] = make_float4(s.x * inv, s.y * inv, s.z * inv, s.w * inv);
        }
    };
    finish_row(0, acc0, z0);
    finish_row(1, acc1, z1);
    finish_row(2, acc2, z2);
    finish_row(3, acc3, z3);
}

extern "C" void kernel_launch(void* const* d_in, const int* in_sizes, int n_in,
                              void* d_out, int out_size, void* d_ws, size_t ws_size,
                              hipStream_t stream) {
    // setup_inputs order: query, key, value, w, mask   (query unused!)
    const float* key   = (const float*)d_in[1];
    const float* value = (const float*)d_in[2];
    const float* w     = (const float*)d_in[3];
    const int*   mask  = (const int*)d_in[4];
    float*       outp  = (float*)d_out;

    float* ks = (float*)d_ws;                    // 16*1024 f32
    unsigned short* bmtab =
        (unsigned short*)(ks + NB * NL);         // 16*1024 x 64 u16 bit table (2MB)

    ksm_kernel <<<NB * NL / 4, 256, 0, stream>>>(key, w, mask, ks, bmtab);
    attn_kernel<<<NB * NL / 32, 512, 0, stream>>>(value, mask, ks, bmtab, outp);
}